// Round 11
// baseline (319.846 us; speedup 1.0000x reference)
//
#include <hip/hip_runtime.h>
#include <hip/hip_bf16.h>

#define N_NODES 100000
#define N_EDGES 3200000
#define F_IN 256
#define D_OUT 64
#define BATCH 4096
#define N_FIELDS 20
#define N_ENTRIES (BATCH * N_FIELDS)          // 81920

#define NBUCKET 512
#define NPB 196                                // nodes per bucket
#define N_PAD (NBUCKET * NPB)                  // 100352
#define EPB 4096                               // edges per scatter block
#define NBLK ((N_EDGES + EPB - 1) / EPB)       // 782
#define BUCKET_CAP 8192                        // fixed region per bucket (6250 expected, 24 sigma)
#define CNT_BLKS (N_ENTRIES / 256)             // 320
#define GEMM_BLKS ((N_NODES + 63) / 64)        // 1563
#define BCAST_BLKS (N_ENTRIES / 16)            // 5120

typedef short bf16x8 __attribute__((ext_vector_type(8)));
typedef float f32x4 __attribute__((ext_vector_type(4)));

static __device__ __forceinline__ unsigned short f2bf_bits(float x) {
    __hip_bfloat16 h = __float2bfloat16(x);
    return *reinterpret_cast<unsigned short*>(&h);
}

// ---- K1: fused front, three independent partitions:
//   A (782):  edge scatter into fixed-capacity bucket regions. Per block:
//             LDS count -> 1 global atomicAdd per bucket reserves a range ->
//             scatter. No hist/colscan/basescan stages, no perBlockCnt.
//   B (320):  refBits marking from x (no entry counting needed anymore).
//   C (1563): MFMA GEMM yf = X @ W (f32, unscaled; wt built from W in-LDS).
__global__ __launch_bounds__(256) void k_front(const uint4* __restrict__ src4,
                                               const uint4* __restrict__ dst4,
                                               unsigned* __restrict__ gCursor,
                                               unsigned* __restrict__ bucketData,
                                               const int* __restrict__ x,
                                               unsigned* __restrict__ refBits,
                                               const float* __restrict__ feat,
                                               const float* __restrict__ W,
                                               float* __restrict__ yf) {
    __shared__ unsigned cur[NBUCKET];
    __shared__ unsigned short wt[64 * 264];
    int tid = threadIdx.x;

    if (blockIdx.x < NBLK) {
        cur[tid] = 0;
        cur[tid + 256] = 0;
        __syncthreads();
        int base4 = blockIdx.x * (EPB / 4);
        // pass 1: local bucket counts
#pragma unroll
        for (int k = 0; k < EPB / 1024; k++) {
            int e4 = base4 + k * 256 + tid;
            if (e4 < N_EDGES / 4) {
                uint4 d = dst4[e4];
                atomicAdd(&cur[d.x / NPB], 1u);
                atomicAdd(&cur[d.y / NPB], 1u);
                atomicAdd(&cur[d.z / NPB], 1u);
                atomicAdd(&cur[d.w / NPB], 1u);
            }
        }
        __syncthreads();
        // reserve global ranges (each thread owns 2 buckets; own-entry R/W only)
        unsigned c0 = cur[tid], c1 = cur[tid + 256];
        unsigned b0 = c0 ? atomicAdd(&gCursor[tid], c0) : 0u;
        unsigned b1 = c1 ? atomicAdd(&gCursor[tid + 256], c1) : 0u;
        __syncthreads();
        cur[tid] = (unsigned)tid * BUCKET_CAP + b0;
        cur[tid + 256] = (unsigned)(tid + 256) * BUCKET_CAP + b1;
        __syncthreads();
        // pass 2: scatter (dst re-read is L1/L2-hot)
#pragma unroll
        for (int k = 0; k < EPB / 1024; k++) {
            int e4 = base4 + k * 256 + tid;
            if (e4 < N_EDGES / 4) {
                uint4 s = src4[e4];
                uint4 d = dst4[e4];
                unsigned ss[4] = {s.x, s.y, s.z, s.w};
                unsigned dd[4] = {d.x, d.y, d.z, d.w};
#pragma unroll
                for (int j = 0; j < 4; j++) {
                    unsigned b = dd[j] / NPB;
                    unsigned ld = dd[j] - b * NPB;
                    unsigned slot = atomicAdd(&cur[b], 1u);
                    if (slot < (b + 1u) * BUCKET_CAP)      // overflow guard (never in practice)
                        bucketData[slot] = ss[j] | (ld << 17);
                }
            }
        }
    } else if (blockIdx.x < NBLK + CNT_BLKS) {
        int ent = (blockIdx.x - NBLK) * 256 + tid;
        if (ent < N_ENTRIES) {
            int node = x[ent];
            atomicOr(&refBits[node >> 5], 1u << (node & 31));
        }
    } else {
        int gb = blockIdx.x - NBLK - CNT_BLKS;
        {
            const float4* wrow = (const float4*)(W + tid * 64);
#pragma unroll
            for (int n4 = 0; n4 < 16; n4++) {
                float4 v = wrow[n4];
                wt[(n4 * 4 + 0) * 264 + tid] = f2bf_bits(v.x);
                wt[(n4 * 4 + 1) * 264 + tid] = f2bf_bits(v.y);
                wt[(n4 * 4 + 2) * 264 + tid] = f2bf_bits(v.z);
                wt[(n4 * 4 + 3) * 264 + tid] = f2bf_bits(v.w);
            }
        }
        __syncthreads();

        int wave = tid >> 6, lane = tid & 63;
        int quad = lane >> 4, m = lane & 15;
        int rowT = gb * 64 + wave * 16;
        int row = rowT + m;
        int rowC = (row < N_NODES) ? row : (N_NODES - 1);
        const float* fb = feat + (size_t)rowC * F_IN + quad * 8;

        f32x4 acc0 = {0.f, 0.f, 0.f, 0.f};
        f32x4 acc1 = acc0, acc2 = acc0, acc3 = acc0;

#pragma unroll
        for (int kk = 0; kk < 8; kk++) {
            float4 x0 = *(const float4*)(fb + kk * 32);
            float4 x1 = *(const float4*)(fb + kk * 32 + 4);
            bf16x8 a;
            a[0] = (short)f2bf_bits(x0.x); a[1] = (short)f2bf_bits(x0.y);
            a[2] = (short)f2bf_bits(x0.z); a[3] = (short)f2bf_bits(x0.w);
            a[4] = (short)f2bf_bits(x1.x); a[5] = (short)f2bf_bits(x1.y);
            a[6] = (short)f2bf_bits(x1.z); a[7] = (short)f2bf_bits(x1.w);
            int kbase = kk * 32 + quad * 8;
            bf16x8 b0 = *(const bf16x8*)&wt[(0 * 16 + m) * 264 + kbase];
            bf16x8 b1 = *(const bf16x8*)&wt[(1 * 16 + m) * 264 + kbase];
            bf16x8 b2 = *(const bf16x8*)&wt[(2 * 16 + m) * 264 + kbase];
            bf16x8 b3 = *(const bf16x8*)&wt[(3 * 16 + m) * 264 + kbase];
            acc0 = __builtin_amdgcn_mfma_f32_16x16x32_bf16(a, b0, acc0, 0, 0, 0);
            acc1 = __builtin_amdgcn_mfma_f32_16x16x32_bf16(a, b1, acc1, 0, 0, 0);
            acc2 = __builtin_amdgcn_mfma_f32_16x16x32_bf16(a, b2, acc2, 0, 0, 0);
            acc3 = __builtin_amdgcn_mfma_f32_16x16x32_bf16(a, b3, acc3, 0, 0, 0);
        }

#pragma unroll
        for (int r = 0; r < 4; r++) {
            int rr = rowT + quad * 4 + r;
            if (rr < N_NODES) {
                size_t o = (size_t)rr * D_OUT + m;
                yf[o]      = acc0[r];
                yf[o + 16] = acc1[r];
                yf[o + 32] = acc2[r];
                yf[o + 48] = acc3[r];
            }
        }
    }
}

// ---- K2: per-bucket CSR build + y finalize (base = b*BUCKET_CAP, cnt from gCursor) ----
__global__ __launch_bounds__(256) void k_bucket_csr(unsigned* __restrict__ bucketData,
                                                    const unsigned* __restrict__ gCursor,
                                                    const unsigned* __restrict__ refBits,
                                                    int* __restrict__ rowStart,
                                                    unsigned short* __restrict__ deg,
                                                    const float* __restrict__ yf,
                                                    unsigned short* __restrict__ y) {
    __shared__ unsigned srcsorted[BUCKET_CAP];
    __shared__ unsigned nodeCount[NPB];
    __shared__ unsigned sscan[256];
    __shared__ unsigned cursor[NPB];
    __shared__ unsigned char refF[NPB];

    int b = blockIdx.x;
    int base = b * BUCKET_CAP;
    int cnt = (int)gCursor[b];
    if (cnt > BUCKET_CAP) cnt = BUCKET_CAP;
    int tid = threadIdx.x;

    for (int j = tid; j < NPB; j += 256) nodeCount[j] = 0;
    __syncthreads();

    for (int i = tid; i < cnt; i += 256) {
        unsigned w = bucketData[base + i];
        atomicAdd(&nodeCount[w >> 17], 1u);
    }
    __syncthreads();

    int firstNode = b * NPB;
    unsigned refCnt = 0;
    if (tid < NPB) {
        int node = firstNode + tid;
        unsigned isRef = (refBits[node >> 5] >> (node & 31)) & 1u;
        refF[tid] = (unsigned char)isRef;
        refCnt = isRef ? nodeCount[tid] : 0;
        deg[node] = (unsigned short)nodeCount[tid];
    }
    sscan[tid] = refCnt;
    __syncthreads();
    for (int off = 1; off < 256; off <<= 1) {
        unsigned t = (tid >= off) ? sscan[tid - off] : 0;
        __syncthreads();
        sscan[tid] += t;
        __syncthreads();
    }

    if (tid < NPB) {
        unsigned excl = sscan[tid] - refCnt;
        rowStart[firstNode + tid] = base + (int)excl;
        cursor[tid] = excl;
    }
    __syncthreads();

    for (int i = tid; i < cnt; i += 256) {
        unsigned w = bucketData[base + i];
        unsigned ld = w >> 17;
        if (refF[ld]) {
            unsigned slot = atomicAdd(&cursor[ld], 1u);
            srcsorted[slot] = w & 0x1FFFFu;
        }
    }
    __syncthreads();

    int refTotal = (int)sscan[255];
    for (int i = tid; i < refTotal; i += 256)
        bucketData[base + i] = srcsorted[i];

    // y finalize: 196 rows x 64 ch, float4 in / uint2 (4 bf16) out.
    for (int idx = tid; idx < NPB * 16; idx += 256) {
        int j = idx >> 4;
        int node = firstNode + j;
        if (node < N_NODES) {
            float ds = rsqrtf((float)nodeCount[j] + 1.0f);
            float4 v = ((const float4*)(yf + (size_t)node * D_OUT))[idx & 15];
            uint2 pw;
            pw.x = (unsigned)f2bf_bits(v.x * ds) | ((unsigned)f2bf_bits(v.y * ds) << 16);
            pw.y = (unsigned)f2bf_bits(v.z * ds) | ((unsigned)f2bf_bits(v.w * ds) << 16);
            ((uint2*)(y + (size_t)node * D_OUT))[idx & 15] = pw;
        }
    }
}

// ---- K3: dedup aggregation -> dense valN[node] (no entry grouping) ----
static __device__ __forceinline__ void acc4(f32x4& a, uint2 v, float msk) {
    a[0] += msk * __uint_as_float(v.x << 16);
    a[1] += msk * __uint_as_float(v.x & 0xffff0000u);
    a[2] += msk * __uint_as_float(v.y << 16);
    a[3] += msk * __uint_as_float(v.y & 0xffff0000u);
}

__global__ __launch_bounds__(256) void k_agg(const unsigned* __restrict__ refBits,
                                             const int* __restrict__ rowStart,
                                             const unsigned short* __restrict__ deg,
                                             const unsigned* __restrict__ sortedSrc,
                                             const unsigned short* __restrict__ y,
                                             const float* __restrict__ b,
                                             float* __restrict__ valN) {
    int g = blockIdx.x * blockDim.x + threadIdx.x;
    int i = g >> 6, lane = g & 63;
    if (i >= N_PAD) return;
    if (!((refBits[i >> 5] >> (i & 31)) & 1u)) return;

    int grp = lane >> 4;
    int m = lane & 15;
    int start = rowStart[i];
    int cnt = deg[i];
    float disI = rsqrtf((float)(cnt + 1));

    uint2 sv = *(const uint2*)(y + ((unsigned)i << 6) + (m << 2));

    f32x4 a0 = {0.f, 0.f, 0.f, 0.f};
    f32x4 a1 = a0, a2 = a0, a3 = a0;

    for (int e = 0; e < cnt; e += 32) {
        int e0 = e + grp,      e1 = e + 4 + grp,  e2 = e + 8 + grp,  e3 = e + 12 + grp;
        int e4 = e + 16 + grp, e5 = e + 20 + grp, e6 = e + 24 + grp, e7 = e + 28 + grp;
        unsigned r0 = (e0 < cnt) ? sortedSrc[start + e0] : (unsigned)i;
        unsigned r1 = (e1 < cnt) ? sortedSrc[start + e1] : (unsigned)i;
        unsigned r2 = (e2 < cnt) ? sortedSrc[start + e2] : (unsigned)i;
        unsigned r3 = (e3 < cnt) ? sortedSrc[start + e3] : (unsigned)i;
        unsigned r4 = (e4 < cnt) ? sortedSrc[start + e4] : (unsigned)i;
        unsigned r5 = (e5 < cnt) ? sortedSrc[start + e5] : (unsigned)i;
        unsigned r6 = (e6 < cnt) ? sortedSrc[start + e6] : (unsigned)i;
        unsigned r7 = (e7 < cnt) ? sortedSrc[start + e7] : (unsigned)i;
        uint2 v0 = *(const uint2*)(y + (r0 << 6) + (m << 2));
        uint2 v1 = *(const uint2*)(y + (r1 << 6) + (m << 2));
        uint2 v2 = *(const uint2*)(y + (r2 << 6) + (m << 2));
        uint2 v3 = *(const uint2*)(y + (r3 << 6) + (m << 2));
        uint2 v4 = *(const uint2*)(y + (r4 << 6) + (m << 2));
        uint2 v5 = *(const uint2*)(y + (r5 << 6) + (m << 2));
        uint2 v6 = *(const uint2*)(y + (r6 << 6) + (m << 2));
        uint2 v7 = *(const uint2*)(y + (r7 << 6) + (m << 2));
        acc4(a0, v0, (e0 < cnt) ? 1.f : 0.f);
        acc4(a1, v1, (e1 < cnt) ? 1.f : 0.f);
        acc4(a2, v2, (e2 < cnt) ? 1.f : 0.f);
        acc4(a3, v3, (e3 < cnt) ? 1.f : 0.f);
        acc4(a0, v4, (e4 < cnt) ? 1.f : 0.f);
        acc4(a1, v5, (e5 < cnt) ? 1.f : 0.f);
        acc4(a2, v6, (e6 < cnt) ? 1.f : 0.f);
        acc4(a3, v7, (e7 < cnt) ? 1.f : 0.f);
    }

    f32x4 s;
#pragma unroll
    for (int c = 0; c < 4; c++) s[c] = (a0[c] + a1[c]) + (a2[c] + a3[c]);
#pragma unroll
    for (int c = 0; c < 4; c++) {
        s[c] += __shfl_xor(s[c], 16, 64);
        s[c] += __shfl_xor(s[c], 32, 64);
    }

    if (grp == 0) {
        float4 b4 = *(const float4*)(b + (m << 2));
        float4 val;
        val.x = disI * (s[0] + __uint_as_float(sv.x << 16)) + b4.x;
        val.y = disI * (s[1] + __uint_as_float(sv.x & 0xffff0000u)) + b4.y;
        val.z = disI * (s[2] + __uint_as_float(sv.y << 16)) + b4.z;
        val.w = disI * (s[3] + __uint_as_float(sv.y & 0xffff0000u)) + b4.w;
        *(float4*)(valN + (size_t)i * D_OUT + (m << 2)) = val;
    }
}

// ---- K4: broadcast valN to entries: out[ent] = valN[x[ent]] ----
__global__ __launch_bounds__(256) void k_bcast(const int* __restrict__ x,
                                               const float* __restrict__ valN,
                                               float* __restrict__ out) {
    int tid = threadIdx.x;
    int ent = blockIdx.x * 16 + (tid >> 4);
    int q = tid & 15;
    int node = x[ent];
    float4 v = ((const float4*)(valN + (size_t)node * D_OUT))[q];
    ((float4*)(out + (size_t)ent * D_OUT))[q] = v;
}

extern "C" void kernel_launch(void* const* d_in, const int* in_sizes, int n_in,
                              void* d_out, int out_size, void* d_ws, size_t ws_size,
                              hipStream_t stream) {
    const float* feat     = (const float*)d_in[0];
    const int* edge_index = (const int*)d_in[1];
    const float* W        = (const float*)d_in[2];
    const float* bsrc     = (const float*)d_in[3];
    const int* x          = (const int*)d_in[4];
    float* out            = (float*)d_out;

    const uint4* src4 = (const uint4*)edge_index;
    const uint4* dst4 = (const uint4*)(edge_index + N_EDGES);

    // workspace layout (256B aligned) — ~82 MB total (ws >= 400 MB per fill).
    char* ws = (char*)d_ws;
    size_t off = 0;
    auto alloc = [&](size_t bytes) {
        size_t o = off;
        off = (off + bytes + 255) & ~(size_t)255;
        return o;
    };
    unsigned* gCursor   = (unsigned*)(ws + alloc((size_t)NBUCKET * 4));
    unsigned* refBits   = (unsigned*)(ws + alloc((size_t)(N_PAD / 8)));
    int* rowStart       = (int*)(ws + alloc((size_t)N_PAD * 4));
    unsigned short* deg = (unsigned short*)(ws + alloc((size_t)N_PAD * 2));
    unsigned* bucketData = (unsigned*)(ws + alloc((size_t)NBUCKET * BUCKET_CAP * 4));
    unsigned short* y   = (unsigned short*)(ws + alloc((size_t)N_NODES * D_OUT * 2));
    float* yf           = (float*)(ws + alloc((size_t)N_NODES * D_OUT * 4));
    float* valN         = (float*)(ws + alloc((size_t)N_PAD * D_OUT * 4));
    (void)ws_size; (void)in_sizes; (void)n_in; (void)out_size;

    const int T = 256;
    (void)hipMemsetAsync(gCursor, 0, (size_t)NBUCKET * 4, stream);
    (void)hipMemsetAsync(refBits, 0, (size_t)(N_PAD / 8), stream);
    k_front<<<NBLK + CNT_BLKS + GEMM_BLKS, T, 0, stream>>>(src4, dst4, gCursor, bucketData,
                                                           x, refBits, feat, W, yf);
    k_bucket_csr<<<NBUCKET, T, 0, stream>>>(bucketData, gCursor, refBits, rowStart, deg, yf, y);
    k_agg<<<((size_t)N_PAD * 64 + T - 1) / T, T, 0, stream>>>(
        refBits, rowStart, deg, bucketData, y, bsrc, valN);
    k_bcast<<<BCAST_BLKS, T, 0, stream>>>(x, valN, out);
}

// Round 13
// 285.385 us; speedup vs baseline: 1.1208x; 1.1208x over previous
//
#include <hip/hip_runtime.h>
#include <hip/hip_bf16.h>

#define N_NODES 100000
#define N_EDGES 3200000
#define F_IN 256
#define D_OUT 64
#define BATCH 4096
#define N_FIELDS 20
#define N_ENTRIES (BATCH * N_FIELDS)          // 81920

#define NBUCKET 512
#define NPB 196                                // nodes per bucket
#define N_PAD (NBUCKET * NPB)                  // 100352
#define EPB 8192                               // edges per scatter block
#define NBLK ((N_EDGES + EPB - 1) / EPB)       // 391
#define BUCKET_CAP 8192                        // fixed region per bucket (6272 expected, 24 sigma)
#define CNT_BLKS (N_ENTRIES / 256)             // 320
#define GEMM_BLKS ((N_NODES + 63) / 64)        // 1563
#define BCAST_BLKS (N_ENTRIES / 16)            // 5120

// LDS overlay offsets (bytes) for the scatter partition
#define SB_BYTES   (EPB * 4)                   // 32768 sortbuf
#define LBE_OFF    SB_BYTES                    // int lbE[513]  -> 2052 B
#define CUR_OFF    (LBE_OFF + 2052)            // unsigned cur[512] -> 2048 B
#define SBG_OFF    (CUR_OFF + 2048)            // unsigned sbG[512] -> 2048 B

typedef short bf16x8 __attribute__((ext_vector_type(8)));
typedef float f32x4 __attribute__((ext_vector_type(4)));

static __device__ __forceinline__ unsigned short f2bf_bits(float x) {
    __hip_bfloat16 h = __float2bfloat16(x);
    return *reinterpret_cast<unsigned short*>(&h);
}

// ---- K1: fused front, three independent partitions:
//   A (391):  edge counting-sort scatter. LDS count -> 1 global atomicAdd per
//             bucket reserves a range (r11-proven) -> LDS-grouped sort (r7-
//             proven) -> per-element binary-search write-out (r7-proven;
//             coalesced 64B-line writes kill the 16x write-allocate
//             amplification of random 4B stores).
//   B (320):  refBits marking from x.
//   C (1563): MFMA GEMM yf = X @ W (f32, unscaled; wt built from W in-LDS).
//   LDS: union of {sortbuf+scan arrays: 38.9KB} and {wt: 33.8KB} -> 4 blk/CU.
__global__ __launch_bounds__(256) void k_front(const uint4* __restrict__ src4,
                                               const uint4* __restrict__ dst4,
                                               unsigned* __restrict__ gCursor,
                                               unsigned* __restrict__ bucketData,
                                               const int* __restrict__ x,
                                               unsigned* __restrict__ refBits,
                                               const float* __restrict__ feat,
                                               const float* __restrict__ W,
                                               float* __restrict__ yf) {
    __shared__ __align__(16) char smem[38928];
    int tid = threadIdx.x;

    if (blockIdx.x < NBLK) {
        unsigned* sortbuf = (unsigned*)smem;
        int*      lbE     = (int*)(smem + LBE_OFF);
        unsigned* cur     = (unsigned*)(smem + CUR_OFF);
        unsigned* sbG     = (unsigned*)(smem + SBG_OFF);

        cur[tid] = 0;
        cur[tid + 256] = 0;
        __syncthreads();
        int base4 = blockIdx.x * (EPB / 4);
        // pass 1: local bucket counts
#pragma unroll
        for (int k = 0; k < EPB / 1024; k++) {
            int e4 = base4 + k * 256 + tid;
            if (e4 < N_EDGES / 4) {
                uint4 d = dst4[e4];
                atomicAdd(&cur[d.x / NPB], 1u);
                atomicAdd(&cur[d.y / NPB], 1u);
                atomicAdd(&cur[d.z / NPB], 1u);
                atomicAdd(&cur[d.w / NPB], 1u);
            }
        }
        __syncthreads();
        unsigned c0 = cur[tid], c1 = cur[tid + 256];
        // reserve global ranges (1 atomic per non-empty bucket per block)
        unsigned g0 = c0 ? atomicAdd(&gCursor[tid], c0) : 0u;
        unsigned g1 = c1 ? atomicAdd(&gCursor[tid + 256], c1) : 0u;
        sbG[tid] = (unsigned)tid * BUCKET_CAP + g0;
        sbG[tid + 256] = (unsigned)(tid + 256) * BUCKET_CAP + g1;
        // inclusive scan of the 512 counts (2 elems/thread Hillis-Steele)
        lbE[tid] = (int)c0;
        lbE[tid + 256] = (int)c1;
        __syncthreads();
        for (int off = 1; off < 512; off <<= 1) {
            int t0 = (tid >= off) ? lbE[tid - off] : 0;
            int t1 = lbE[tid + 256 - off];
            __syncthreads();
            lbE[tid] += t0;
            lbE[tid + 256] += t1;
            __syncthreads();
        }
        int incl0 = lbE[tid], incl1 = lbE[tid + 256];
        __syncthreads();
        lbE[tid] = incl0 - (int)c0;             // exclusive base
        lbE[tid + 256] = incl1 - (int)c1;
        cur[tid] = (unsigned)(incl0 - (int)c0); // running cursor
        cur[tid + 256] = (unsigned)(incl1 - (int)c1);
        if (tid == 255) lbE[NBUCKET] = incl1;   // total edges this block
        __syncthreads();
        // pass 2: scatter edges into LDS grouped by bucket (dst re-read L2-hot)
#pragma unroll
        for (int k = 0; k < EPB / 1024; k++) {
            int e4 = base4 + k * 256 + tid;
            if (e4 < N_EDGES / 4) {
                uint4 s = src4[e4];
                uint4 d = dst4[e4];
                unsigned ss[4] = {s.x, s.y, s.z, s.w};
                unsigned dd[4] = {d.x, d.y, d.z, d.w};
#pragma unroll
                for (int j = 0; j < 4; j++) {
                    unsigned b = dd[j] / NPB;
                    unsigned ld = dd[j] - b * NPB;
                    unsigned slot = atomicAdd(&cur[b], 1u);
                    sortbuf[slot] = ss[j] | (ld << 17);
                }
            }
        }
        __syncthreads();
        // write-out (r7-proven): per-element binary search over lbE;
        // consecutive lanes share the search path -> LDS broadcast reads,
        // and writes land in contiguous 64B-line runs per bucket segment.
        int ecnt = lbE[NBUCKET];
        for (int i = tid; i < ecnt; i += 256) {
            unsigned w = sortbuf[i];
            int lo = 0, hi = NBUCKET;
            while (hi - lo > 1) {
                int mid = (lo + hi) >> 1;
                if (lbE[mid] <= i) lo = mid; else hi = mid;
            }
            unsigned dstIdx = sbG[lo] + (unsigned)(i - lbE[lo]);
            if (dstIdx < (unsigned)(lo + 1) * BUCKET_CAP)  // overflow guard
                bucketData[dstIdx] = w;
        }
    } else if (blockIdx.x < NBLK + CNT_BLKS) {
        int ent = (blockIdx.x - NBLK) * 256 + tid;
        if (ent < N_ENTRIES) {
            int node = x[ent];
            atomicOr(&refBits[node >> 5], 1u << (node & 31));
        }
    } else {
        unsigned short* wt = (unsigned short*)smem;   // [64*264]
        int gb = blockIdx.x - NBLK - CNT_BLKS;
        {
            const float4* wrow = (const float4*)(W + tid * 64);
#pragma unroll
            for (int n4 = 0; n4 < 16; n4++) {
                float4 v = wrow[n4];
                wt[(n4 * 4 + 0) * 264 + tid] = f2bf_bits(v.x);
                wt[(n4 * 4 + 1) * 264 + tid] = f2bf_bits(v.y);
                wt[(n4 * 4 + 2) * 264 + tid] = f2bf_bits(v.z);
                wt[(n4 * 4 + 3) * 264 + tid] = f2bf_bits(v.w);
            }
        }
        __syncthreads();

        int wave = tid >> 6, lane = tid & 63;
        int quad = lane >> 4, m = lane & 15;
        int rowT = gb * 64 + wave * 16;
        int row = rowT + m;
        int rowC = (row < N_NODES) ? row : (N_NODES - 1);
        const float* fb = feat + (size_t)rowC * F_IN + quad * 8;

        f32x4 acc0 = {0.f, 0.f, 0.f, 0.f};
        f32x4 acc1 = acc0, acc2 = acc0, acc3 = acc0;

#pragma unroll
        for (int kk = 0; kk < 8; kk++) {
            float4 x0 = *(const float4*)(fb + kk * 32);
            float4 x1 = *(const float4*)(fb + kk * 32 + 4);
            bf16x8 a;
            a[0] = (short)f2bf_bits(x0.x); a[1] = (short)f2bf_bits(x0.y);
            a[2] = (short)f2bf_bits(x0.z); a[3] = (short)f2bf_bits(x0.w);
            a[4] = (short)f2bf_bits(x1.x); a[5] = (short)f2bf_bits(x1.y);
            a[6] = (short)f2bf_bits(x1.z); a[7] = (short)f2bf_bits(x1.w);
            int kbase = kk * 32 + quad * 8;
            bf16x8 b0 = *(const bf16x8*)&wt[(0 * 16 + m) * 264 + kbase];
            bf16x8 b1 = *(const bf16x8*)&wt[(1 * 16 + m) * 264 + kbase];
            bf16x8 b2 = *(const bf16x8*)&wt[(2 * 16 + m) * 264 + kbase];
            bf16x8 b3 = *(const bf16x8*)&wt[(3 * 16 + m) * 264 + kbase];
            acc0 = __builtin_amdgcn_mfma_f32_16x16x32_bf16(a, b0, acc0, 0, 0, 0);
            acc1 = __builtin_amdgcn_mfma_f32_16x16x32_bf16(a, b1, acc1, 0, 0, 0);
            acc2 = __builtin_amdgcn_mfma_f32_16x16x32_bf16(a, b2, acc2, 0, 0, 0);
            acc3 = __builtin_amdgcn_mfma_f32_16x16x32_bf16(a, b3, acc3, 0, 0, 0);
        }

#pragma unroll
        for (int r = 0; r < 4; r++) {
            int rr = rowT + quad * 4 + r;
            if (rr < N_NODES) {
                size_t o = (size_t)rr * D_OUT + m;
                yf[o]      = acc0[r];
                yf[o + 16] = acc1[r];
                yf[o + 32] = acc2[r];
                yf[o + 48] = acc3[r];
            }
        }
    }
}

// ---- K2: per-bucket CSR build + y finalize (base = b*BUCKET_CAP, cnt from gCursor) ----
__global__ __launch_bounds__(256) void k_bucket_csr(unsigned* __restrict__ bucketData,
                                                    const unsigned* __restrict__ gCursor,
                                                    const unsigned* __restrict__ refBits,
                                                    int* __restrict__ rowStart,
                                                    unsigned short* __restrict__ deg,
                                                    const float* __restrict__ yf,
                                                    unsigned short* __restrict__ y) {
    __shared__ unsigned srcsorted[BUCKET_CAP];
    __shared__ unsigned nodeCount[NPB];
    __shared__ unsigned sscan[256];
    __shared__ unsigned cursor[NPB];
    __shared__ unsigned char refF[NPB];

    int b = blockIdx.x;
    int base = b * BUCKET_CAP;
    int cnt = (int)gCursor[b];
    if (cnt > BUCKET_CAP) cnt = BUCKET_CAP;
    int tid = threadIdx.x;

    for (int j = tid; j < NPB; j += 256) nodeCount[j] = 0;
    __syncthreads();

    for (int i = tid; i < cnt; i += 256) {
        unsigned w = bucketData[base + i];
        atomicAdd(&nodeCount[w >> 17], 1u);
    }
    __syncthreads();

    int firstNode = b * NPB;
    unsigned refCnt = 0;
    if (tid < NPB) {
        int node = firstNode + tid;
        unsigned isRef = (refBits[node >> 5] >> (node & 31)) & 1u;
        refF[tid] = (unsigned char)isRef;
        refCnt = isRef ? nodeCount[tid] : 0;
        deg[node] = (unsigned short)nodeCount[tid];
    }
    sscan[tid] = refCnt;
    __syncthreads();
    for (int off = 1; off < 256; off <<= 1) {
        unsigned t = (tid >= off) ? sscan[tid - off] : 0;
        __syncthreads();
        sscan[tid] += t;
        __syncthreads();
    }

    if (tid < NPB) {
        unsigned excl = sscan[tid] - refCnt;
        rowStart[firstNode + tid] = base + (int)excl;
        cursor[tid] = excl;
    }
    __syncthreads();

    for (int i = tid; i < cnt; i += 256) {
        unsigned w = bucketData[base + i];
        unsigned ld = w >> 17;
        if (refF[ld]) {
            unsigned slot = atomicAdd(&cursor[ld], 1u);
            srcsorted[slot] = w & 0x1FFFFu;
        }
    }
    __syncthreads();

    int refTotal = (int)sscan[255];
    for (int i = tid; i < refTotal; i += 256)
        bucketData[base + i] = srcsorted[i];

    // y finalize: 196 rows x 64 ch, float4 in / uint2 (4 bf16) out.
    for (int idx = tid; idx < NPB * 16; idx += 256) {
        int j = idx >> 4;
        int node = firstNode + j;
        if (node < N_NODES) {
            float ds = rsqrtf((float)nodeCount[j] + 1.0f);
            float4 v = ((const float4*)(yf + (size_t)node * D_OUT))[idx & 15];
            uint2 pw;
            pw.x = (unsigned)f2bf_bits(v.x * ds) | ((unsigned)f2bf_bits(v.y * ds) << 16);
            pw.y = (unsigned)f2bf_bits(v.z * ds) | ((unsigned)f2bf_bits(v.w * ds) << 16);
            ((uint2*)(y + (size_t)node * D_OUT))[idx & 15] = pw;
        }
    }
}

// ---- K3: dedup aggregation -> dense valN[node] ----
static __device__ __forceinline__ void acc4(f32x4& a, uint2 v, float msk) {
    a[0] += msk * __uint_as_float(v.x << 16);
    a[1] += msk * __uint_as_float(v.x & 0xffff0000u);
    a[2] += msk * __uint_as_float(v.y << 16);
    a[3] += msk * __uint_as_float(v.y & 0xffff0000u);
}

__global__ __launch_bounds__(256) void k_agg(const unsigned* __restrict__ refBits,
                                             const int* __restrict__ rowStart,
                                             const unsigned short* __restrict__ deg,
                                             const unsigned* __restrict__ sortedSrc,
                                             const unsigned short* __restrict__ y,
                                             const float* __restrict__ b,
                                             float* __restrict__ valN) {
    int g = blockIdx.x * blockDim.x + threadIdx.x;
    int i = g >> 6, lane = g & 63;
    if (i >= N_PAD) return;
    if (!((refBits[i >> 5] >> (i & 31)) & 1u)) return;

    int grp = lane >> 4;
    int m = lane & 15;
    int start = rowStart[i];
    int cnt = deg[i];
    float disI = rsqrtf((float)(cnt + 1));

    uint2 sv = *(const uint2*)(y + ((unsigned)i << 6) + (m << 2));

    f32x4 a0 = {0.f, 0.f, 0.f, 0.f};
    f32x4 a1 = a0, a2 = a0, a3 = a0;

    for (int e = 0; e < cnt; e += 32) {
        int e0 = e + grp,      e1 = e + 4 + grp,  e2 = e + 8 + grp,  e3 = e + 12 + grp;
        int e4 = e + 16 + grp, e5 = e + 20 + grp, e6 = e + 24 + grp, e7 = e + 28 + grp;
        unsigned r0 = (e0 < cnt) ? sortedSrc[start + e0] : (unsigned)i;
        unsigned r1 = (e1 < cnt) ? sortedSrc[start + e1] : (unsigned)i;
        unsigned r2 = (e2 < cnt) ? sortedSrc[start + e2] : (unsigned)i;
        unsigned r3 = (e3 < cnt) ? sortedSrc[start + e3] : (unsigned)i;
        unsigned r4 = (e4 < cnt) ? sortedSrc[start + e4] : (unsigned)i;
        unsigned r5 = (e5 < cnt) ? sortedSrc[start + e5] : (unsigned)i;
        unsigned r6 = (e6 < cnt) ? sortedSrc[start + e6] : (unsigned)i;
        unsigned r7 = (e7 < cnt) ? sortedSrc[start + e7] : (unsigned)i;
        uint2 v0 = *(const uint2*)(y + (r0 << 6) + (m << 2));
        uint2 v1 = *(const uint2*)(y + (r1 << 6) + (m << 2));
        uint2 v2 = *(const uint2*)(y + (r2 << 6) + (m << 2));
        uint2 v3 = *(const uint2*)(y + (r3 << 6) + (m << 2));
        uint2 v4 = *(const uint2*)(y + (r4 << 6) + (m << 2));
        uint2 v5 = *(const uint2*)(y + (r5 << 6) + (m << 2));
        uint2 v6 = *(const uint2*)(y + (r6 << 6) + (m << 2));
        uint2 v7 = *(const uint2*)(y + (r7 << 6) + (m << 2));
        acc4(a0, v0, (e0 < cnt) ? 1.f : 0.f);
        acc4(a1, v1, (e1 < cnt) ? 1.f : 0.f);
        acc4(a2, v2, (e2 < cnt) ? 1.f : 0.f);
        acc4(a3, v3, (e3 < cnt) ? 1.f : 0.f);
        acc4(a0, v4, (e4 < cnt) ? 1.f : 0.f);
        acc4(a1, v5, (e5 < cnt) ? 1.f : 0.f);
        acc4(a2, v6, (e6 < cnt) ? 1.f : 0.f);
        acc4(a3, v7, (e7 < cnt) ? 1.f : 0.f);
    }

    f32x4 s;
#pragma unroll
    for (int c = 0; c < 4; c++) s[c] = (a0[c] + a1[c]) + (a2[c] + a3[c]);
#pragma unroll
    for (int c = 0; c < 4; c++) {
        s[c] += __shfl_xor(s[c], 16, 64);
        s[c] += __shfl_xor(s[c], 32, 64);
    }

    if (grp == 0) {
        float4 b4 = *(const float4*)(b + (m << 2));
        float4 val;
        val.x = disI * (s[0] + __uint_as_float(sv.x << 16)) + b4.x;
        val.y = disI * (s[1] + __uint_as_float(sv.x & 0xffff0000u)) + b4.y;
        val.z = disI * (s[2] + __uint_as_float(sv.y << 16)) + b4.z;
        val.w = disI * (s[3] + __uint_as_float(sv.y & 0xffff0000u)) + b4.w;
        *(float4*)(valN + (size_t)i * D_OUT + (m << 2)) = val;
    }
}

// ---- K4: broadcast valN to entries: out[ent] = valN[x[ent]] ----
__global__ __launch_bounds__(256) void k_bcast(const int* __restrict__ x,
                                               const float* __restrict__ valN,
                                               float* __restrict__ out) {
    int tid = threadIdx.x;
    int ent = blockIdx.x * 16 + (tid >> 4);
    int q = tid & 15;
    int node = x[ent];
    float4 v = ((const float4*)(valN + (size_t)node * D_OUT))[q];
    ((float4*)(out + (size_t)ent * D_OUT))[q] = v;
}

extern "C" void kernel_launch(void* const* d_in, const int* in_sizes, int n_in,
                              void* d_out, int out_size, void* d_ws, size_t ws_size,
                              hipStream_t stream) {
    const float* feat     = (const float*)d_in[0];
    const int* edge_index = (const int*)d_in[1];
    const float* W        = (const float*)d_in[2];
    const float* bsrc     = (const float*)d_in[3];
    const int* x          = (const int*)d_in[4];
    float* out            = (float*)d_out;

    const uint4* src4 = (const uint4*)edge_index;
    const uint4* dst4 = (const uint4*)(edge_index + N_EDGES);

    // workspace layout (256B aligned) — ~82 MB total (ws >= 400 MB per fill).
    char* ws = (char*)d_ws;
    size_t off = 0;
    auto alloc = [&](size_t bytes) {
        size_t o = off;
        off = (off + bytes + 255) & ~(size_t)255;
        return o;
    };
    unsigned* gCursor   = (unsigned*)(ws + alloc((size_t)NBUCKET * 4));
    unsigned* refBits   = (unsigned*)(ws + alloc((size_t)(N_PAD / 8)));
    int* rowStart       = (int*)(ws + alloc((size_t)N_PAD * 4));
    unsigned short* deg = (unsigned short*)(ws + alloc((size_t)N_PAD * 2));
    unsigned* bucketData = (unsigned*)(ws + alloc((size_t)NBUCKET * BUCKET_CAP * 4));
    unsigned short* y   = (unsigned short*)(ws + alloc((size_t)N_NODES * D_OUT * 2));
    float* yf           = (float*)(ws + alloc((size_t)N_NODES * D_OUT * 4));
    float* valN         = (float*)(ws + alloc((size_t)N_PAD * D_OUT * 4));
    (void)ws_size; (void)in_sizes; (void)n_in; (void)out_size;

    const int T = 256;
    (void)hipMemsetAsync(gCursor, 0, (size_t)NBUCKET * 4, stream);
    (void)hipMemsetAsync(refBits, 0, (size_t)(N_PAD / 8), stream);
    k_front<<<NBLK + CNT_BLKS + GEMM_BLKS, T, 0, stream>>>(src4, dst4, gCursor, bucketData,
                                                           x, refBits, feat, W, yf);
    k_bucket_csr<<<NBUCKET, T, 0, stream>>>(bucketData, gCursor, refBits, rowStart, deg, yf, y);
    k_agg<<<((size_t)N_PAD * 64 + T - 1) / T, T, 0, stream>>>(
        refBits, rowStart, deg, bucketData, y, bsrc, valN);
    k_bcast<<<BCAST_BLKS, T, 0, stream>>>(x, valN, out);
}